// Round 5
// baseline (557.067 us; speedup 1.0000x reference)
//
#include <hip/hip_runtime.h>
#include <hip/hip_bf16.h>
#include <math.h>

#define Tn 8
#define Hn 32
#define Wn 32
#define Pn 8192      // Tn*Hn*Wn
#define Cn 256
#define CINn 128
#define NTAP 147     // 3*7*7

typedef short s8v __attribute__((ext_vector_type(8)));   // 8 x bf16 (4 VGPRs)
typedef float f4v __attribute__((ext_vector_type(4)));   // MFMA acc
typedef __hip_bfloat16 bf16;

__device__ __forceinline__ float gelu_f(float v) {
    return 0.5f * v * (1.0f + tanhf(0.7978845608028654f * (v + 0.044715f * v * v * v)));
}

// ---------------- cast f32 -> bf16 (same layout) ----------------
__global__ __launch_bounds__(256) void cast_bf16_k(const float* __restrict__ in,
                                                   bf16* __restrict__ out) {
    const int i = blockIdx.x * 256 + threadIdx.x;
    const float4 v = ((const float4*)in)[i];
    out[i * 4 + 0] = __float2bfloat16(v.x);
    out[i * 4 + 1] = __float2bfloat16(v.y);
    out[i * 4 + 2] = __float2bfloat16(v.z);
    out[i * 4 + 3] = __float2bfloat16(v.w);
}

// ---------------- transpose+cast: in f32 [R][C] -> out bf16 [C][R] ----------------
__global__ __launch_bounds__(256) void tcast_k(const float* __restrict__ in,
                                               bf16* __restrict__ out, int R, int C) {
    __shared__ float tile[32][33];
    const int tid = (int)threadIdx.x, tx = tid & 31, ty = tid >> 5;
    const int rb = blockIdx.y << 5, cb = blockIdx.x << 5;
#pragma unroll
    for (int p = 0; p < 4; ++p)
        tile[ty + p * 8][tx] = in[(size_t)(rb + ty + p * 8) * C + cb + tx];
    __syncthreads();
#pragma unroll
    for (int p = 0; p < 4; ++p)
        out[(size_t)(cb + ty + p * 8) * R + rb + tx] = __float2bfloat16(tile[tx][ty + p * 8]);
}

// ---------------- transpose f32: in [R][C] -> out [C][R] ----------------
__global__ __launch_bounds__(256) void transpose32_k(const float* __restrict__ in,
                                                     float* __restrict__ out, int R, int C) {
    __shared__ float tile[32][33];
    const int tid = (int)threadIdx.x, tx = tid & 31, ty = tid >> 5;
    const int rb = blockIdx.y << 5, cb = blockIdx.x << 5;
#pragma unroll
    for (int p = 0; p < 4; ++p)
        tile[ty + p * 8][tx] = in[(size_t)(rb + ty + p * 8) * C + cb + tx];
    __syncthreads();
#pragma unroll
    for (int p = 0; p < 4; ++p)
        out[(size_t)(cb + ty + p * 8) * R + rb + tx] = tile[tx][ty + p * 8];
}

// ---------------- bf16 MFMA GEMM: C[M,N] = f(A[M,K] @ Wt[N,K]^T + bias) ----------------
template <int BN, int MODE>
__global__ __launch_bounds__(256) void gemm_bf16_k(
        const bf16* __restrict__ A, const bf16* __restrict__ Wt,
        const float* __restrict__ bias, float* __restrict__ Cf,
        bf16* __restrict__ Cb, int M, int N, int K) {
    constexpr int BM = 128;
    constexpr int NW = BN / 2;     // wave n-extent
    constexpr int NF = BN / 32;    // n-frags per wave
    __shared__ s8v As[4 * BM];
    __shared__ s8v Bs[4 * BN];

    const int tid = (int)threadIdx.x;
    const int lane = tid & 63, wid = tid >> 6;
    const int wm = wid & 1, wn = wid >> 1;
    const int l15 = lane & 15, l4 = lane >> 4;
    const int m0 = blockIdx.y * BM;
    const int n0 = blockIdx.x * BN;

    f4v acc[4][NF];
#pragma unroll
    for (int i = 0; i < 4; ++i)
#pragma unroll
        for (int j = 0; j < NF; ++j)
#pragma unroll
            for (int r = 0; r < 4; ++r) acc[i][j][r] = 0.f;

    const int am = tid & (BM - 1), ak8 = tid >> 7;
    const int bn_ = tid % BN, bk8 = tid / BN;
    const bf16* Arow = A + (size_t)(m0 + am) * K + ak8 * 8;
    const bf16* Brow = Wt + (size_t)(n0 + bn_) * K + bk8 * 8;

    for (int kb = 0; kb < K; kb += 32) {
        As[tid]       = *(const s8v*)(Arow + kb);
        As[tid + 256] = *(const s8v*)(Arow + kb + 16);
        if (BN == 128) {
            Bs[tid]       = *(const s8v*)(Brow + kb);
            Bs[tid + 256] = *(const s8v*)(Brow + kb + 16);
        } else {
            Bs[tid] = *(const s8v*)(Brow + kb);
        }
        __syncthreads();

        s8v af[4], bfr[NF];
#pragma unroll
        for (int i = 0; i < 4; ++i)
            af[i] = As[l4 * BM + wm * 64 + i * 16 + l15];
#pragma unroll
        for (int j = 0; j < NF; ++j)
            bfr[j] = Bs[l4 * BN + wn * NW + j * 16 + l15];
#pragma unroll
        for (int i = 0; i < 4; ++i)
#pragma unroll
            for (int j = 0; j < NF; ++j)
                acc[i][j] = __builtin_amdgcn_mfma_f32_16x16x32_bf16(af[i], bfr[j], acc[i][j], 0, 0, 0);
        __syncthreads();
    }

#pragma unroll
    for (int i = 0; i < 4; ++i) {
        const int rbase = m0 + wm * 64 + i * 16 + l4 * 4;
#pragma unroll
        for (int j = 0; j < NF; ++j) {
            const int col = n0 + wn * NW + j * 16 + l15;
            const float bv = bias[col];
#pragma unroll
            for (int r = 0; r < 4; ++r) {
                const size_t idx = (size_t)(rbase + r) * N + col;
                const float v = acc[i][j][r] + bv;
                if (MODE == 0) Cf[idx] = v;
                if (MODE == 1) Cb[idx] = __float2bfloat16(gelu_f(v));
                if (MODE == 2) Cf[idx] += v;
            }
        }
    }
}

// ---------------- fused 8-iteration depthwise circular conv SSM ----------------
// One block (256 threads) per channel. Thread owns one full (t,h) row of 32 w.
// 2 LDS plane buffers ping-pong (read it&1, write (it+1)&1) -> 1 sync/iter.
// Swizzle: chunk c of plane-row r stored at r*8 + (c ^ sx(r)),
//   sx(r) = (r + (r>>3)) & 7  -- distinct across BOTH consecutive and strided
//   8-lane octets (round-4's c^(r&7) was 8-way conflicted for strided octets).
#define SF(S, i) (((i) & 3) == 0 ? S[(i) >> 2].x : ((i) & 3) == 1 ? S[(i) >> 2].y \
                : ((i) & 3) == 2 ? S[(i) >> 2].z : S[(i) >> 2].w)

#define LOADS(S, body) do {                                                   \
    const int kt_ = (body) / 7;                                               \
    const int kh_ = (body) % 7;                                               \
    const int sr_ = tp[kt_] + hm[kh_];                                        \
    const int rb_ = sr_ * 8;                                                  \
    const int sx_ = (sr_ + (sr_ >> 3)) & 7;                                   \
    S[0] = sp[rb_ + (0 ^ sx_)];  S[1] = sp[rb_ + (1 ^ sx_)];                  \
    S[2] = sp[rb_ + (2 ^ sx_)];  S[3] = sp[rb_ + (3 ^ sx_)];                  \
    S[4] = sp[rb_ + (4 ^ sx_)];  S[5] = sp[rb_ + (5 ^ sx_)];                  \
    S[6] = sp[rb_ + (6 ^ sx_)];  S[7] = sp[rb_ + (7 ^ sx_)];                  \
} while (0)

#define COMPUTE(S, body) do {                                                 \
    const float4 wq0_ = *(const float4*)&wP[wbase + (body) * 8];              \
    const float4 wq1_ = *(const float4*)&wP[wbase + (body) * 8 + 4];          \
    const float wv_[7] = {wq0_.x, wq0_.y, wq0_.z, wq0_.w,                     \
                          wq1_.x, wq1_.y, wq1_.z};                            \
    _Pragma("unroll")                                                         \
    for (int kw_ = 0; kw_ < 7; ++kw_) {                                       \
        _Pragma("unroll")                                                     \
        for (int ww_ = 0; ww_ < 32; ++ww_) {                                  \
            const int ix_ = (ww_ - kw_ + 35) & 31;                            \
            acc[ww_] = fmaf(wv_[kw_], SF(S, ix_), acc[ww_]);                  \
        }                                                                     \
    }                                                                         \
} while (0)

__global__ __launch_bounds__(256) void conv_ssm_k(
        const float* __restrict__ xp,   // [C][8192]
        const float* __restrict__ Ak,   // [C][147]
        const float* __restrict__ Bk,   // [C][147]
        float* __restrict__ hpo) {      // [C][8192]
    __shared__ float4 P[2][2048];
    __shared__ float wP[2 * 21 * 8];    // [sel(B=0,A=1)][body][kw], 8-padded

    const int c = blockIdx.x;
    const int tid = (int)threadIdx.x;
    const int t = tid >> 5, hh = tid & 31;

    if (tid < NTAP) {
        const int body = tid / 7, kw = tid % 7;
        wP[body * 8 + kw] = Bk[(size_t)c * NTAP + tid];
        wP[168 + body * 8 + kw] = 0.9f * tanhf(Ak[(size_t)c * NTAP + tid]);
    }

    // precomputed circular row offsets (static-indexed after unroll)
    int tp[3], hm[7];
#pragma unroll
    for (int kt = 0; kt < 3; ++kt) tp[kt] = ((t - kt + 9) & 7) << 5;
#pragma unroll
    for (int kh = 0; kh < 7; ++kh) hm[kh] = (hh - kh + 35) & 31;

    {   // stage x plane: coalesced global reads, swizzled LDS writes
        const float4* src = (const float4*)(xp + (size_t)c * Pn);
#pragma unroll
        for (int j = 0; j < 8; ++j) {
            const int g = j * 256 + tid;
            const int r = g >> 3;
            P[0][r * 8 + ((g & 7) ^ ((r + (r >> 3)) & 7))] = src[g];
        }
    }
    float hsum[32];
#pragma unroll
    for (int i = 0; i < 32; ++i) hsum[i] = 0.f;
    __syncthreads();

    const int osx = (tid + (tid >> 3)) & 7;   // own-row swizzle for writes
#pragma unroll 1
    for (int it = 0; it < 8; ++it) {
        const int wbase = (it == 0) ? 0 : 168;
        const float4* sp = P[it & 1];
        float4* dp = P[(it + 1) & 1];
        float acc[32];
#pragma unroll
        for (int i = 0; i < 32; ++i) acc[i] = 0.f;

        float4 sA[8], sB[8];
        LOADS(sA, 0);
#pragma unroll 1
        for (int b = 0; b < 20; b += 2) {
            LOADS(sB, b + 1);
            COMPUTE(sA, b);
            LOADS(sA, b + 2);
            COMPUTE(sB, b + 1);
        }
        COMPUTE(sA, 20);

#pragma unroll
        for (int i = 0; i < 32; ++i) hsum[i] += acc[i];
        if (it < 7) {
#pragma unroll
            for (int j = 0; j < 8; ++j)
                dp[tid * 8 + (j ^ osx)] =
                    make_float4(acc[j * 4], acc[j * 4 + 1], acc[j * 4 + 2], acc[j * 4 + 3]);
        }
        __syncthreads();
    }

    float4* o = (float4*)(hpo + (size_t)c * Pn + tid * 32);
#pragma unroll
    for (int j = 0; j < 8; ++j)
        o[j] = make_float4(hsum[j * 4], hsum[j * 4 + 1], hsum[j * 4 + 2], hsum[j * 4 + 3]);
}

// ---------------- x += LN(h)*scale + bias ; also emit x in bf16 ----------------
__global__ __launch_bounds__(256) void ln_res_k(
        const float4* __restrict__ h4, const float* __restrict__ scale,
        const float* __restrict__ bias, float4* __restrict__ x4,
        bf16* __restrict__ xb) {
    const int p = blockIdx.x * 4 + ((int)threadIdx.x >> 6);
    const int lane = (int)threadIdx.x & 63;
    const float4 v = h4[p * 64 + lane];
    float s = v.x + v.y + v.z + v.w;
    float ss = v.x * v.x + v.y * v.y + v.z * v.z + v.w * v.w;
#pragma unroll
    for (int off = 32; off; off >>= 1) {
        s += __shfl_xor(s, off);
        ss += __shfl_xor(ss, off);
    }
    const float mu = s * (1.0f / 256.0f);
    const float var = ss * (1.0f / 256.0f) - mu * mu;
    const float rs = rsqrtf(var + 1e-6f);
    const float4 sc = ((const float4*)scale)[lane];
    const float4 bi = ((const float4*)bias)[lane];
    float4 xv = x4[p * 64 + lane];
    xv.x += (v.x - mu) * rs * sc.x + bi.x;
    xv.y += (v.y - mu) * rs * sc.y + bi.y;
    xv.z += (v.z - mu) * rs * sc.z + bi.z;
    xv.w += (v.w - mu) * rs * sc.w + bi.w;
    x4[p * 64 + lane] = xv;
    bf16* xbp = xb + (size_t)p * Cn + lane * 4;
    xbp[0] = __float2bfloat16(xv.x);
    xbp[1] = __float2bfloat16(xv.y);
    xbp[2] = __float2bfloat16(xv.z);
    xbp[3] = __float2bfloat16(xv.w);
}

// ---------------- feat = mean over (h,w) ----------------
__global__ void feat_part_k(const float* __restrict__ x, float* __restrict__ part) {
    const int t = blockIdx.x, sgm = blockIdx.y;
    const int c = (int)threadIdx.x;
    float acc = 0.f;
    const float* xp_ = x + ((size_t)t * 1024 + sgm * 128) * Cn + c;
    for (int p = 0; p < 128; ++p) acc += xp_[(size_t)p * Cn];
    part[(t * 8 + sgm) * Cn + c] = acc;
}
__global__ void feat_reduce_k(const float* __restrict__ part, float* __restrict__ feat) {
    const int t = blockIdx.x;
    const int c = (int)threadIdx.x;
    float s = 0.f;
    for (int j = 0; j < 8; ++j) s += part[(t * 8 + j) * Cn + c];
    feat[t * Cn + c] = s * (1.0f / 1024.0f);
}

// ---------------- heads ----------------
__global__ __launch_bounds__(256) void heads_k(
        const float* __restrict__ feat, const float* __restrict__ qp,
        const float* __restrict__ traj_w, const float* __restrict__ traj_b,
        const float* __restrict__ occ_w, const float* __restrict__ occ_b,
        float* __restrict__ out) {
    __shared__ float fs[Tn * Cn];
    __shared__ float proj[Tn][3];
    const int tid = (int)threadIdx.x;
    for (int i = tid; i < Tn * Cn; i += 256) fs[i] = feat[i];
    __syncthreads();
    if (tid < 24) {
        const int t = tid / 3, j = tid % 3;
        float s = 0.f;
        for (int c = 0; c < Cn; ++c) {
            const float w = (j < 2) ? traj_w[c * 2 + j] : occ_w[c];
            s += fs[t * Cn + c] * w;
        }
        s += (j < 2) ? traj_b[j] : occ_b[0];
        proj[t][j] = s;
    }
    __syncthreads();
    const int n = tid;
#pragma unroll
    for (int t = 0; t < Tn; ++t) {
        out[(n * Tn + t) * 2 + 0] = proj[t][0] + qp[n * 3 + 1];
        out[(n * Tn + t) * 2 + 1] = proj[t][1] + qp[n * 3 + 2];
        out[4096 + n * Tn + t] = 1.0f / (1.0f + expf(-proj[t][2]));
    }
}

extern "C" void kernel_launch(void* const* d_in, const int* in_sizes, int n_in,
                              void* d_out, int out_size, void* d_ws, size_t ws_size,
                              hipStream_t stream) {
    const float* video = (const float*)d_in[0];
    const float* qp    = (const float*)d_in[1];
    const float* convw = (const float*)d_in[2];
    const float* convb = (const float*)d_in[3];
    const float* Ak    = (const float*)d_in[4];
    const float* Bk    = (const float*)d_in[5];
    const float* ln_s  = (const float*)d_in[6];
    const float* ln_b  = (const float*)d_in[7];
    const float* w1    = (const float*)d_in[8];
    const float* b1    = (const float*)d_in[9];
    const float* w2    = (const float*)d_in[10];
    const float* b2    = (const float*)d_in[11];
    const float* tw    = (const float*)d_in[12];
    const float* tb    = (const float*)d_in[13];
    const float* ow    = (const float*)d_in[14];
    const float* ob    = (const float*)d_in[15];

    char* wsb = (char*)d_ws;
    float* x   = (float*)wsb;            wsb += (size_t)Pn * Cn * 4;
    float* h   = (float*)wsb;            wsb += (size_t)Pn * Cn * 4;
    float* xpl = (float*)wsb;            wsb += (size_t)Pn * Cn * 4;
    float* hpl = (float*)wsb;            wsb += (size_t)Pn * Cn * 4;
    bf16*  xb  = (bf16*)wsb;             wsb += (size_t)Pn * Cn * 2;
    bf16*  mb  = (bf16*)wsb;             wsb += (size_t)Pn * 1024 * 2;
    bf16*  vb  = (bf16*)wsb;             wsb += (size_t)Pn * CINn * 2;
    bf16*  cwT = (bf16*)wsb;             wsb += (size_t)Cn * CINn * 2;
    bf16*  w1T = (bf16*)wsb;             wsb += (size_t)3 * 1024 * Cn * 2;
    bf16*  w2T = (bf16*)wsb;             wsb += (size_t)3 * Cn * 1024 * 2;
    float* feat = (float*)wsb;           wsb += (size_t)Tn * Cn * 4;
    float* part = (float*)wsb;           wsb += (size_t)64 * Cn * 4;

    cast_bf16_k<<<(Pn * CINn) / 1024, 256, 0, stream>>>(video, vb);
    tcast_k<<<dim3(Cn / 32, CINn / 32), 256, 0, stream>>>(convw, cwT, CINn, Cn);
    for (int i = 0; i < 3; ++i) {
        tcast_k<<<dim3(1024 / 32, Cn / 32), 256, 0, stream>>>(
            w1 + (size_t)i * Cn * 1024, w1T + (size_t)i * 1024 * Cn, Cn, 1024);
        tcast_k<<<dim3(Cn / 32, 1024 / 32), 256, 0, stream>>>(
            w2 + (size_t)i * 1024 * Cn, w2T + (size_t)i * Cn * 1024, 1024, Cn);
    }

    gemm_bf16_k<64, 0><<<dim3(Cn / 64, Pn / 128), 256, 0, stream>>>(
        vb, cwT, convb, x, nullptr, Pn, Cn, CINn);

    for (int i = 0; i < 3; ++i) {
        transpose32_k<<<dim3(Cn / 32, Pn / 32), 256, 0, stream>>>(x, xpl, Pn, Cn);
        conv_ssm_k<<<Cn, 256, 0, stream>>>(xpl, Ak + (size_t)i * Cn * NTAP,
                                           Bk + (size_t)i * Cn * NTAP, hpl);
        transpose32_k<<<dim3(Pn / 32, Cn / 32), 256, 0, stream>>>(hpl, h, Cn, Pn);
        ln_res_k<<<Pn / 4, 256, 0, stream>>>((const float4*)h, ln_s + i * Cn,
                                             ln_b + i * Cn, (float4*)x, xb);
        gemm_bf16_k<128, 1><<<dim3(1024 / 128, Pn / 128), 256, 0, stream>>>(
            xb, w1T + (size_t)i * 1024 * Cn, b1 + (size_t)i * 1024, nullptr, mb,
            Pn, 1024, Cn);
        gemm_bf16_k<64, 2><<<dim3(Cn / 64, Pn / 128), 256, 0, stream>>>(
            mb, w2T + (size_t)i * Cn * 1024, b2 + (size_t)i * Cn, x, nullptr,
            Pn, Cn, 1024);
    }

    feat_part_k<<<dim3(Tn, 8), 256, 0, stream>>>(x, part);
    feat_reduce_k<<<Tn, 256, 0, stream>>>(part, feat);
    heads_k<<<1, 256, 0, stream>>>(feat, qp, tw, tb, ow, ob, (float*)d_out);
}